// Round 5
// baseline (4385.626 us; speedup 1.0000x reference)
//
#include <hip/hip_runtime.h>

#define Bdim 64
#define Ndim 512
#define Hdim 2048
#define KSPLIT 16
#define KRANGE 128
#define KCHUNK 64
#define OCHUNK 32
#define NCHUNK 8
#define LNEPS 1e-5f

typedef unsigned short u16;

__device__ __forceinline__ u16 f2bf(float f) {
    unsigned int u = __float_as_uint(f);
    return (u16)((u + 0x7FFFu + ((u >> 16) & 1u)) >> 16);
}
__device__ __forceinline__ float bf2f(u16 s) {
    return __uint_as_float(((unsigned int)s) << 16);
}

// Partial GEMV (R1-proven core): part[ks][b][o] = sum_{k in ks} X[b,k]*Weff[o,k]
// WMODE 0: Weff[o,k] = W[o*H+k]  (Y = X @ W^T)
// WMODE 1: Weff[o,k] = W[k*H+o]  (Y = X @ W)
// Grid 1024 = 16 k-splits x 64 o-chunks(32). 4 blocks/CU, 16 waves/CU.
// No fences, no atomics, no consumer-side sums (R3/R4 lessons).
template<int WMODE>
__global__ __launch_bounds__(256, 4)
void gemv_main(const float* __restrict__ X, const float* __restrict__ W,
               float* __restrict__ part)
{
    __shared__ float Xs[64][68];
    __shared__ float Ws[OCHUNK][68];
    const int t  = threadIdx.x;
    const int oc = blockIdx.x & 63;   // 64 o-chunks of 32
    const int ks = blockIdx.x >> 6;   // 16 k-splits
    const int o0 = oc * OCHUNK;
    const int kb = ks * KRANGE;
    const int og = t & 7;             // o-group of 4
    const int bg = t >> 3;            // b pair
    float acc[2][4];
#pragma unroll
    for (int j = 0; j < 2; ++j)
#pragma unroll
        for (int oi = 0; oi < 4; ++oi) acc[j][oi] = 0.f;

#pragma unroll
    for (int kc = 0; kc < KRANGE; kc += KCHUNK) {
        const int k0 = kb + kc;
        // stage X[64][64]
#pragma unroll
        for (int i = 0; i < 4; ++i) {
            int flat = i * 256 + t;
            int row  = flat >> 4;
            int c4   = flat & 15;
            float4 v = *(const float4*)(X + (size_t)row * Hdim + k0 + c4 * 4);
            *(float4*)(&Xs[row][c4 * 4]) = v;
        }
        // stage W tile as Ws[o_local][k_local]
        if (WMODE == 0) {
#pragma unroll
            for (int i = 0; i < 2; ++i) {
                int flat = i * 256 + t;
                int row  = flat >> 4;   // o_local 0..31
                int c4   = flat & 15;
                float4 v = *(const float4*)(W + (size_t)(o0 + row) * Hdim + k0 + c4 * 4);
                *(float4*)(&Ws[row][c4 * 4]) = v;
            }
        } else {
#pragma unroll
            for (int i = 0; i < 2; ++i) {
                int flat = i * 256 + t;
                int row  = flat >> 3;   // k_local 0..63
                int c4   = flat & 7;    // o quad
                float4 v = *(const float4*)(W + (size_t)(k0 + row) * Hdim + o0 + c4 * 4);
                Ws[c4 * 4 + 0][row] = v.x;
                Ws[c4 * 4 + 1][row] = v.y;
                Ws[c4 * 4 + 2][row] = v.z;
                Ws[c4 * 4 + 3][row] = v.w;
            }
        }
        __syncthreads();
#pragma unroll
        for (int kk = 0; kk < KCHUNK; kk += 4) {
            float4 x0 = *(const float4*)(&Xs[bg * 2 + 0][kk]);
            float4 x1 = *(const float4*)(&Xs[bg * 2 + 1][kk]);
#pragma unroll
            for (int oi = 0; oi < 4; ++oi) {
                float4 w = *(const float4*)(&Ws[og * 4 + oi][kk]);
                acc[0][oi] += x0.x * w.x + x0.y * w.y + x0.z * w.z + x0.w * w.w;
                acc[1][oi] += x1.x * w.x + x1.y * w.y + x1.z * w.z + x1.w * w.w;
            }
        }
        __syncthreads();
    }
#pragma unroll
    for (int j = 0; j < 2; ++j) {
        const int b = bg * 2 + j;
#pragma unroll
        for (int oi = 0; oi < 4; ++oi)
            part[(size_t)(ks * 64 + b) * Hdim + o0 + og * 4 + oi] = acc[j][oi];
    }
}

// Y[b,o] (=|+=) sum_s part[s][b][o] (+ bias[o]); optionally also write out.
template<int HASBIAS, int ACC, int FINAL>
__global__ __launch_bounds__(256)
void combine(const float* __restrict__ part, const float* __restrict__ bias,
             float* __restrict__ Y, float* __restrict__ out, int has_loss)
{
    const int flat4 = blockIdx.x * 256 + threadIdx.x;   // 0..32767
    const size_t e  = (size_t)flat4 * 4;
    const int o     = (int)(e & (Hdim - 1));
    float4 v;
    if (HASBIAS) v = *(const float4*)(bias + o);
    else         v = make_float4(0.f, 0.f, 0.f, 0.f);
#pragma unroll
    for (int s = 0; s < KSPLIT; ++s) {
        float4 p = *(const float4*)(part + (size_t)s * (64 * Hdim) + e);
        v.x += p.x; v.y += p.y; v.z += p.z; v.w += p.w;
    }
    if (ACC) {
        float4 a = *(const float4*)(Y + e);
        v.x += a.x; v.y += a.y; v.z += a.z; v.w += a.w;
    }
    *(float4*)(Y + e) = v;
    if (FINAL) {
        *(float4*)(out + e) = v;
        if (has_loss && flat4 == 0) out[Bdim * Hdim] = 0.f;
    }
}

// One (b, 8-row n-chunk): scores -> local softmax -> partial weighted sum.
// FIRST: read f32 lfb and also write bf16 cache; else read bf16 cache.
template<int FIRST>
__global__ __launch_bounds__(256, 4)
void flash_chunk(const float* __restrict__ lfb, const u16* __restrict__ lfb16r,
                 u16* __restrict__ lfb16w, const float* __restrict__ thetal,
                 float scale, u16* __restrict__ up,
                 float* __restrict__ wm, float* __restrict__ wz)
{
    __shared__ u16 T[NCHUNK][Hdim];   // 32 KB
    __shared__ float th[Hdim];        // 8 KB
    __shared__ float sc[NCHUNK];
    __shared__ float wts[NCHUNK];
    const int t  = threadIdx.x;
    const int b  = blockIdx.x >> 6;
    const int ch = blockIdx.x & 63;
    const size_t nbase = (size_t)b * Ndim + ch * NCHUNK;
#pragma unroll
    for (int i = 0; i < 16; ++i) {
        int flat4 = i * 256 + t;
        int row   = flat4 >> 9;
        int c4    = flat4 & 511;
        if (FIRST) {
            float4 v = *(const float4*)(lfb + (nbase + row) * Hdim + c4 * 4);
            ushort4 u4;
            u4.x = f2bf(v.x); u4.y = f2bf(v.y); u4.z = f2bf(v.z); u4.w = f2bf(v.w);
            *(ushort4*)(&T[row][c4 * 4]) = u4;
            *(ushort4*)(lfb16w + (nbase + row) * Hdim + c4 * 4) = u4;
        } else {
            ushort4 u4 = *(const ushort4*)(lfb16r + (nbase + row) * Hdim + c4 * 4);
            *(ushort4*)(&T[row][c4 * 4]) = u4;
        }
    }
#pragma unroll
    for (int i = 0; i < 2; ++i) {
        int c = (i * 256 + t) * 4;
        float4 v = *(const float4*)(thetal + (size_t)b * Hdim + c);
        *(float4*)(&th[c]) = v;
    }
    __syncthreads();
    const int wv = t >> 6, ln = t & 63;
#pragma unroll
    for (int q = 0; q < 2; ++q) {
        int n = wv * 2 + q;
        float a = 0.f;
#pragma unroll
        for (int i = 0; i < 8; ++i) {
            int c = ln * 4 + i * 256;
            ushort4 x = *(const ushort4*)(&T[n][c]);
            float4 y  = *(const float4*)(&th[c]);
            a += bf2f(x.x) * y.x + bf2f(x.y) * y.y + bf2f(x.z) * y.z + bf2f(x.w) * y.w;
        }
#pragma unroll
        for (int off = 32; off; off >>= 1) a += __shfl_xor(a, off, 64);
        if (ln == 0) sc[n] = a * scale;
    }
    __syncthreads();
    float m = sc[0];
#pragma unroll
    for (int n = 1; n < NCHUNK; ++n) m = fmaxf(m, sc[n]);
    if (t < NCHUNK) wts[t] = expf(sc[t] - m);
    __syncthreads();
    if (t == 0) {
        float z = 0.f;
#pragma unroll
        for (int n = 0; n < NCHUNK; ++n) z += wts[n];
        wm[blockIdx.x] = m;
        wz[blockIdx.x] = z;
    }
#pragma unroll
    for (int i = 0; i < 8; ++i) {
        int c = t + i * 256;
        float a = 0.f;
#pragma unroll
        for (int n = 0; n < NCHUNK; ++n) a += wts[n] * bf2f(T[n][c]);
        up[(size_t)blockIdx.x * Hdim + c] = f2bf(a);
    }
}

__global__ __launch_bounds__(256)
void flash_comb(const u16* __restrict__ up, const float* __restrict__ wm,
                const float* __restrict__ wz, float* __restrict__ u)
{
    __shared__ float mm[64], zz[64], ee[64];
    const int t  = threadIdx.x;
    const int b  = blockIdx.x >> 3;
    const int sl = blockIdx.x & 7;
    if (t < 64) { mm[t] = wm[b * 64 + t]; zz[t] = wz[b * 64 + t]; }
    __syncthreads();
    float mg = mm[0];
#pragma unroll
    for (int i = 1; i < 64; ++i) mg = fmaxf(mg, mm[i]);
    if (t < 64) ee[t] = expf(mm[t] - mg);
    __syncthreads();
    float Z = 0.f;
#pragma unroll
    for (int i = 0; i < 64; ++i) Z += zz[i] * ee[i];
    const float inv = 1.f / Z;
    const int col = sl * 256 + t;
    float a = 0.f;
#pragma unroll 8
    for (int ch = 0; ch < 64; ++ch)
        a += ee[ch] * bf2f(up[(size_t)(b * 64 + ch) * Hdim + col]);
    u[(size_t)b * Hdim + col] = a * inv;
}

// r = relu(layernorm(sum_s part[s][b][:] + bias))
__global__ __launch_bounds__(256)
void ln_relu_part(const float* __restrict__ part, const float* __restrict__ bias,
                  float* __restrict__ r)
{
    __shared__ float trow[Hdim];
    __shared__ float red[8];
    const int t = threadIdx.x, b = blockIdx.x;
    float sum = 0.f, sq = 0.f;
#pragma unroll
    for (int i = 0; i < 2; ++i) {
        int c = (i * 256 + t) * 4;
        float4 v = *(const float4*)(bias + c);
#pragma unroll
        for (int s = 0; s < KSPLIT; ++s) {
            float4 p = *(const float4*)(part + ((size_t)(s * 64 + b)) * Hdim + c);
            v.x += p.x; v.y += p.y; v.z += p.z; v.w += p.w;
        }
        *(float4*)(&trow[c]) = v;
        sum += v.x + v.y + v.z + v.w;
        sq  += v.x * v.x + v.y * v.y + v.z * v.z + v.w * v.w;
    }
#pragma unroll
    for (int off = 32; off; off >>= 1) {
        sum += __shfl_xor(sum, off, 64);
        sq  += __shfl_xor(sq,  off, 64);
    }
    if ((t & 63) == 0) { red[t >> 6] = sum; red[4 + (t >> 6)] = sq; }
    __syncthreads();
    sum = red[0] + red[1] + red[2] + red[3];
    sq  = red[4] + red[5] + red[6] + red[7];
    const float mu   = sum * (1.f / Hdim);
    const float var  = sq * (1.f / Hdim) - mu * mu;
    const float rstd = rsqrtf(var + LNEPS);
#pragma unroll
    for (int i = 0; i < 2; ++i) {
        int c = (i * 256 + t) * 4;
        float4 v = *(const float4*)(&trow[c]);
        float4 o;
        o.x = fmaxf(0.f, (v.x - mu) * rstd);
        o.y = fmaxf(0.f, (v.y - mu) * rstd);
        o.z = fmaxf(0.f, (v.z - mu) * rstd);
        o.w = fmaxf(0.f, (v.w - mu) * rstd);
        *(float4*)(r + (size_t)b * Hdim + c) = o;
    }
}

extern "C" void kernel_launch(void* const* d_in, const int* in_sizes, int n_in,
                              void* d_out, int out_size, void* d_ws, size_t ws_size,
                              hipStream_t stream) {
    (void)in_sizes; (void)n_in; (void)ws_size;
    const float* clip = (const float*)d_in[0];
    const float* lfb  = (const float*)d_in[1];
    const float* Wc   = (const float*)d_in[2];
    const float* bc   = (const float*)d_in[3];
    const float* Wl   = (const float*)d_in[4];
    const float* bl   = (const float*)d_in[5];
    const float* Wt   = (const float*)d_in[6];
    const float* bt   = (const float*)d_in[7];
    const float* Wp   = (const float*)d_in[8];
    // d_in[9] = bp: cancels in softmax (per-row constant) -> unused
    const float* Wg   = (const float*)d_in[10];
    const float* bg   = (const float*)d_in[11];
    const float* Wo   = (const float*)d_in[12];
    const float* bo   = (const float*)d_in[13];
    float* out = (float*)d_out;

    // Workspace layout in f32 slots; u16 buffers counted in f32 slots.
    // A..r: 6 x 131072 = 786432
    // PA: 16*64*2048 = 2097152            -> [786432, 2883584)
    // wm: 4096                            -> [2883584, 2887680)
    // wz: 4096                            -> [2887680, 2891776)
    // up: 4096*2048 u16 = 4194304 f32     -> [2891776, 7086080)
    // lfb16: 64*512*2048 u16 = 33554432   -> [7086080, 40640512)  (~163 MB)
    float* wsf    = (float*)d_ws;
    float* A      = wsf;
    float* theta  = wsf + 131072;
    float* thetap = wsf + 262144;
    float* thetal = wsf + 393216;
    float* u      = wsf + 524288;
    float* r      = wsf + 655360;
    float* PA     = wsf + 786432;
    float* wm     = wsf + 2883584;
    float* wz     = wsf + 2887680;
    u16*   up     = (u16*)(wsf + 2891776);
    u16*   lfb16  = (u16*)(wsf + 7086080);

    const float scale = 0.022097086912079608f;   // 1/sqrt(2048)
    dim3 blk(256);
    const int has_loss = (out_size > Bdim * Hdim) ? 1 : 0;

    // A = clip @ Wc^T + bc
    gemv_main<0><<<1024, blk, 0, stream>>>(clip, Wc, PA);
    combine<1,0,0><<<128, blk, 0, stream>>>(PA, bc, A, nullptr, 0);

    for (int l = 0; l < 3; ++l) {
        // theta = A @ Wt^T + bt
        gemv_main<0><<<1024, blk, 0, stream>>>(A, Wt, PA);
        combine<1,0,0><<<128, blk, 0, stream>>>(PA, bt, theta, nullptr, 0);
        // thetap = theta @ Wp
        gemv_main<1><<<1024, blk, 0, stream>>>(theta, Wp, PA);
        combine<0,0,0><<<128, blk, 0, stream>>>(PA, nullptr, thetap, nullptr, 0);
        // thetal = thetap @ Wl
        gemv_main<1><<<1024, blk, 0, stream>>>(thetap, Wl, PA);
        combine<0,0,0><<<128, blk, 0, stream>>>(PA, nullptr, thetal, nullptr, 0);
        // fused scores/softmax/weighted-sum over lfb
        if (l == 0)
            flash_chunk<1><<<4096, blk, 0, stream>>>(lfb, nullptr, lfb16, thetal, scale, up, wm, wz);
        else
            flash_chunk<0><<<4096, blk, 0, stream>>>(nullptr, lfb16, nullptr, thetal, scale, up, wm, wz);
        flash_comb<<<512, blk, 0, stream>>>(up, wm, wz, u);
        // s = u @ Wl^T + bl
        gemv_main<0><<<1024, blk, 0, stream>>>(u, Wl, PA);
        combine<1,0,0><<<128, blk, 0, stream>>>(PA, bl, theta, nullptr, 0);
        // t = s @ Wg^T + bg (bg added in LN kernel); r = relu(LN(t))
        gemv_main<0><<<1024, blk, 0, stream>>>(theta, Wg, PA);
        ln_relu_part<<<64, blk, 0, stream>>>(PA, bg, r);
        // A += r @ Wo^T + bo   (last layer also writes out + loss)
        gemv_main<0><<<1024, blk, 0, stream>>>(r, Wo, PA);
        if (l < 2)
            combine<1,1,0><<<128, blk, 0, stream>>>(PA, bo, A, nullptr, 0);
        else
            combine<1,1,1><<<128, blk, 0, stream>>>(PA, bo, A, out, has_loss);
    }
}

// Round 6
// 569.407 us; speedup vs baseline: 7.7021x; 7.7021x over previous
//
#include <hip/hip_runtime.h>

#define Bdim 64
#define Ndim 512
#define Hdim 2048
#define KSPLIT 16
#define KRANGE 128
#define KCHUNK 64
#define OCHUNK 32
#define NCHUNK 8
#define LNEPS 1e-5f

typedef unsigned short u16;

__device__ __forceinline__ u16 f2bf(float f) {
    unsigned int u = __float_as_uint(f);
    return (u16)((u + 0x7FFFu + ((u >> 16) & 1u)) >> 16);
}
__device__ __forceinline__ float bf2f(u16 s) {
    return __uint_as_float(((unsigned int)s) << 16);
}

// Partial GEMV (R1-proven core): part[ks][b][o] = sum_{k in ks} X[b,k]*Weff[o,k]
// WMODE 0: Weff[o,k] = W[o*H+k]  (Y = X @ W^T)
// WMODE 1: Weff[o,k] = W[k*H+o]  (Y = X @ W)
// Grid 1024 = 16 k-splits x 64 o-chunks(32).
// NOTE: no min-waves launch_bounds clause — forcing 4 waves/SIMD capped VGPR
// at 64 and spilled ~800 MB/dispatch to scratch (R5 counters). Low natural
// pressure: global loads go straight to LDS, acc is 8 regs.
template<int WMODE>
__global__ __launch_bounds__(256)
void gemv_main(const float* __restrict__ X, const float* __restrict__ W,
               float* __restrict__ part)
{
    __shared__ float Xs[64][68];
    __shared__ float Ws[OCHUNK][68];
    const int t  = threadIdx.x;
    const int oc = blockIdx.x & 63;   // 64 o-chunks of 32
    const int ks = blockIdx.x >> 6;   // 16 k-splits
    const int o0 = oc * OCHUNK;
    const int kb = ks * KRANGE;
    const int og = t & 7;             // o-group of 4
    const int bg = t >> 3;            // b pair
    float acc[2][4];
#pragma unroll
    for (int j = 0; j < 2; ++j)
#pragma unroll
        for (int oi = 0; oi < 4; ++oi) acc[j][oi] = 0.f;

    for (int kc = 0; kc < KRANGE; kc += KCHUNK) {   // plain loop: keep live ranges small
        const int k0 = kb + kc;
        // stage X[64][64]
#pragma unroll
        for (int i = 0; i < 4; ++i) {
            int flat = i * 256 + t;
            int row  = flat >> 4;
            int c4   = flat & 15;
            float4 v = *(const float4*)(X + (size_t)row * Hdim + k0 + c4 * 4);
            *(float4*)(&Xs[row][c4 * 4]) = v;
        }
        // stage W tile as Ws[o_local][k_local]
        if (WMODE == 0) {
#pragma unroll
            for (int i = 0; i < 2; ++i) {
                int flat = i * 256 + t;
                int row  = flat >> 4;   // o_local 0..31
                int c4   = flat & 15;
                float4 v = *(const float4*)(W + (size_t)(o0 + row) * Hdim + k0 + c4 * 4);
                *(float4*)(&Ws[row][c4 * 4]) = v;
            }
        } else {
#pragma unroll
            for (int i = 0; i < 2; ++i) {
                int flat = i * 256 + t;
                int row  = flat >> 3;   // k_local 0..63
                int c4   = flat & 7;    // o quad
                float4 v = *(const float4*)(W + (size_t)(k0 + row) * Hdim + o0 + c4 * 4);
                Ws[c4 * 4 + 0][row] = v.x;
                Ws[c4 * 4 + 1][row] = v.y;
                Ws[c4 * 4 + 2][row] = v.z;
                Ws[c4 * 4 + 3][row] = v.w;
            }
        }
        __syncthreads();
#pragma unroll
        for (int kk = 0; kk < KCHUNK; kk += 4) {
            float4 x0 = *(const float4*)(&Xs[bg * 2 + 0][kk]);
            float4 x1 = *(const float4*)(&Xs[bg * 2 + 1][kk]);
#pragma unroll
            for (int oi = 0; oi < 4; ++oi) {
                float4 w = *(const float4*)(&Ws[og * 4 + oi][kk]);
                acc[0][oi] += x0.x * w.x + x0.y * w.y + x0.z * w.z + x0.w * w.w;
                acc[1][oi] += x1.x * w.x + x1.y * w.y + x1.z * w.z + x1.w * w.w;
            }
        }
        __syncthreads();
    }
#pragma unroll
    for (int j = 0; j < 2; ++j) {
        const int b = bg * 2 + j;
#pragma unroll
        for (int oi = 0; oi < 4; ++oi)
            part[(size_t)(ks * 64 + b) * Hdim + o0 + og * 4 + oi] = acc[j][oi];
    }
}

// Y[b,o] (=|+=) sum_s part[s][b][o] (+ bias[o]); optionally also write out.
template<int HASBIAS, int ACC, int FINAL>
__global__ __launch_bounds__(256)
void combine(const float* __restrict__ part, const float* __restrict__ bias,
             float* __restrict__ Y, float* __restrict__ out, int has_loss)
{
    const int flat4 = blockIdx.x * 256 + threadIdx.x;   // 0..32767
    const size_t e  = (size_t)flat4 * 4;
    const int o     = (int)(e & (Hdim - 1));
    float4 v;
    if (HASBIAS) v = *(const float4*)(bias + o);
    else         v = make_float4(0.f, 0.f, 0.f, 0.f);
#pragma unroll
    for (int s = 0; s < KSPLIT; ++s) {
        float4 p = *(const float4*)(part + (size_t)s * (64 * Hdim) + e);
        v.x += p.x; v.y += p.y; v.z += p.z; v.w += p.w;
    }
    if (ACC) {
        float4 a = *(const float4*)(Y + e);
        v.x += a.x; v.y += a.y; v.z += a.z; v.w += a.w;
    }
    *(float4*)(Y + e) = v;
    if (FINAL) {
        *(float4*)(out + e) = v;
        if (has_loss && flat4 == 0) out[Bdim * Hdim] = 0.f;
    }
}

// One (b, 8-row n-chunk): scores -> local softmax -> partial weighted sum.
// FIRST: read f32 lfb and also write bf16 cache; else read bf16 cache.
template<int FIRST>
__global__ __launch_bounds__(256, 4)
void flash_chunk(const float* __restrict__ lfb, const u16* __restrict__ lfb16r,
                 u16* __restrict__ lfb16w, const float* __restrict__ thetal,
                 float scale, u16* __restrict__ up,
                 float* __restrict__ wm, float* __restrict__ wz)
{
    __shared__ u16 T[NCHUNK][Hdim];   // 32 KB
    __shared__ float th[Hdim];        // 8 KB
    __shared__ float sc[NCHUNK];
    __shared__ float wts[NCHUNK];
    const int t  = threadIdx.x;
    const int b  = blockIdx.x >> 6;
    const int ch = blockIdx.x & 63;
    const size_t nbase = (size_t)b * Ndim + ch * NCHUNK;
#pragma unroll
    for (int i = 0; i < 16; ++i) {
        int flat4 = i * 256 + t;
        int row   = flat4 >> 9;
        int c4    = flat4 & 511;
        if (FIRST) {
            float4 v = *(const float4*)(lfb + (nbase + row) * Hdim + c4 * 4);
            ushort4 u4;
            u4.x = f2bf(v.x); u4.y = f2bf(v.y); u4.z = f2bf(v.z); u4.w = f2bf(v.w);
            *(ushort4*)(&T[row][c4 * 4]) = u4;
            *(ushort4*)(lfb16w + (nbase + row) * Hdim + c4 * 4) = u4;
        } else {
            ushort4 u4 = *(const ushort4*)(lfb16r + (nbase + row) * Hdim + c4 * 4);
            *(ushort4*)(&T[row][c4 * 4]) = u4;
        }
    }
#pragma unroll
    for (int i = 0; i < 2; ++i) {
        int c = (i * 256 + t) * 4;
        float4 v = *(const float4*)(thetal + (size_t)b * Hdim + c);
        *(float4*)(&th[c]) = v;
    }
    __syncthreads();
    const int wv = t >> 6, ln = t & 63;
#pragma unroll
    for (int q = 0; q < 2; ++q) {
        int n = wv * 2 + q;
        float a = 0.f;
#pragma unroll
        for (int i = 0; i < 8; ++i) {
            int c = ln * 4 + i * 256;
            ushort4 x = *(const ushort4*)(&T[n][c]);
            float4 y  = *(const float4*)(&th[c]);
            a += bf2f(x.x) * y.x + bf2f(x.y) * y.y + bf2f(x.z) * y.z + bf2f(x.w) * y.w;
        }
#pragma unroll
        for (int off = 32; off; off >>= 1) a += __shfl_xor(a, off, 64);
        if (ln == 0) sc[n] = a * scale;
    }
    __syncthreads();
    float m = sc[0];
#pragma unroll
    for (int n = 1; n < NCHUNK; ++n) m = fmaxf(m, sc[n]);
    if (t < NCHUNK) wts[t] = expf(sc[t] - m);
    __syncthreads();
    if (t == 0) {
        float z = 0.f;
#pragma unroll
        for (int n = 0; n < NCHUNK; ++n) z += wts[n];
        wm[blockIdx.x] = m;
        wz[blockIdx.x] = z;
    }
#pragma unroll
    for (int i = 0; i < 8; ++i) {
        int c = t + i * 256;
        float a = 0.f;
#pragma unroll
        for (int n = 0; n < NCHUNK; ++n) a += wts[n] * bf2f(T[n][c]);
        up[(size_t)blockIdx.x * Hdim + c] = f2bf(a);
    }
}

__global__ __launch_bounds__(256)
void flash_comb(const u16* __restrict__ up, const float* __restrict__ wm,
                const float* __restrict__ wz, float* __restrict__ u)
{
    __shared__ float mm[64], zz[64], ee[64];
    const int t  = threadIdx.x;
    const int b  = blockIdx.x >> 3;
    const int sl = blockIdx.x & 7;
    if (t < 64) { mm[t] = wm[b * 64 + t]; zz[t] = wz[b * 64 + t]; }
    __syncthreads();
    float mg = mm[0];
#pragma unroll
    for (int i = 1; i < 64; ++i) mg = fmaxf(mg, mm[i]);
    if (t < 64) ee[t] = expf(mm[t] - mg);
    __syncthreads();
    float Z = 0.f;
#pragma unroll
    for (int i = 0; i < 64; ++i) Z += zz[i] * ee[i];
    const float inv = 1.f / Z;
    const int col = sl * 256 + t;
    float a = 0.f;
#pragma unroll 8
    for (int ch = 0; ch < 64; ++ch)
        a += ee[ch] * bf2f(up[(size_t)(b * 64 + ch) * Hdim + col]);
    u[(size_t)b * Hdim + col] = a * inv;
}

// r = relu(layernorm(sum_s part[s][b][:] + bias))
__global__ __launch_bounds__(256)
void ln_relu_part(const float* __restrict__ part, const float* __restrict__ bias,
                  float* __restrict__ r)
{
    __shared__ float trow[Hdim];
    __shared__ float red[8];
    const int t = threadIdx.x, b = blockIdx.x;
    float sum = 0.f, sq = 0.f;
#pragma unroll
    for (int i = 0; i < 2; ++i) {
        int c = (i * 256 + t) * 4;
        float4 v = *(const float4*)(bias + c);
#pragma unroll
        for (int s = 0; s < KSPLIT; ++s) {
            float4 p = *(const float4*)(part + ((size_t)(s * 64 + b)) * Hdim + c);
            v.x += p.x; v.y += p.y; v.z += p.z; v.w += p.w;
        }
        *(float4*)(&trow[c]) = v;
        sum += v.x + v.y + v.z + v.w;
        sq  += v.x * v.x + v.y * v.y + v.z * v.z + v.w * v.w;
    }
#pragma unroll
    for (int off = 32; off; off >>= 1) {
        sum += __shfl_xor(sum, off, 64);
        sq  += __shfl_xor(sq,  off, 64);
    }
    if ((t & 63) == 0) { red[t >> 6] = sum; red[4 + (t >> 6)] = sq; }
    __syncthreads();
    sum = red[0] + red[1] + red[2] + red[3];
    sq  = red[4] + red[5] + red[6] + red[7];
    const float mu   = sum * (1.f / Hdim);
    const float var  = sq * (1.f / Hdim) - mu * mu;
    const float rstd = rsqrtf(var + LNEPS);
#pragma unroll
    for (int i = 0; i < 2; ++i) {
        int c = (i * 256 + t) * 4;
        float4 v = *(const float4*)(&trow[c]);
        float4 o;
        o.x = fmaxf(0.f, (v.x - mu) * rstd);
        o.y = fmaxf(0.f, (v.y - mu) * rstd);
        o.z = fmaxf(0.f, (v.z - mu) * rstd);
        o.w = fmaxf(0.f, (v.w - mu) * rstd);
        *(float4*)(r + (size_t)b * Hdim + c) = o;
    }
}

extern "C" void kernel_launch(void* const* d_in, const int* in_sizes, int n_in,
                              void* d_out, int out_size, void* d_ws, size_t ws_size,
                              hipStream_t stream) {
    (void)in_sizes; (void)n_in; (void)ws_size;
    const float* clip = (const float*)d_in[0];
    const float* lfb  = (const float*)d_in[1];
    const float* Wc   = (const float*)d_in[2];
    const float* bc   = (const float*)d_in[3];
    const float* Wl   = (const float*)d_in[4];
    const float* bl   = (const float*)d_in[5];
    const float* Wt   = (const float*)d_in[6];
    const float* bt   = (const float*)d_in[7];
    const float* Wp   = (const float*)d_in[8];
    // d_in[9] = bp: cancels in softmax (per-row constant) -> unused
    const float* Wg   = (const float*)d_in[10];
    const float* bg   = (const float*)d_in[11];
    const float* Wo   = (const float*)d_in[12];
    const float* bo   = (const float*)d_in[13];
    float* out = (float*)d_out;

    // Workspace layout in f32 slots; u16 buffers counted in f32 slots.
    float* wsf    = (float*)d_ws;
    float* A      = wsf;
    float* theta  = wsf + 131072;
    float* thetap = wsf + 262144;
    float* thetal = wsf + 393216;
    float* u      = wsf + 524288;
    float* r      = wsf + 655360;
    float* PA     = wsf + 786432;            // 16*64*2048 = 2097152
    float* wm     = wsf + 2883584;           // 4096
    float* wz     = wsf + 2887680;           // 4096
    u16*   up     = (u16*)(wsf + 2891776);   // 4096*2048 u16 = 4194304 f32 slots
    u16*   lfb16  = (u16*)(wsf + 7086080);   // 64*512*2048 u16 = 33554432 f32 slots

    const float scale = 0.022097086912079608f;   // 1/sqrt(2048)
    dim3 blk(256);
    const int has_loss = (out_size > Bdim * Hdim) ? 1 : 0;

    // A = clip @ Wc^T + bc
    gemv_main<0><<<1024, blk, 0, stream>>>(clip, Wc, PA);
    combine<1,0,0><<<128, blk, 0, stream>>>(PA, bc, A, nullptr, 0);

    for (int l = 0; l < 3; ++l) {
        // theta = A @ Wt^T + bt
        gemv_main<0><<<1024, blk, 0, stream>>>(A, Wt, PA);
        combine<1,0,0><<<128, blk, 0, stream>>>(PA, bt, theta, nullptr, 0);
        // thetap = theta @ Wp
        gemv_main<1><<<1024, blk, 0, stream>>>(theta, Wp, PA);
        combine<0,0,0><<<128, blk, 0, stream>>>(PA, nullptr, thetap, nullptr, 0);
        // thetal = thetap @ Wl
        gemv_main<1><<<1024, blk, 0, stream>>>(thetap, Wl, PA);
        combine<0,0,0><<<128, blk, 0, stream>>>(PA, nullptr, thetal, nullptr, 0);
        // fused scores/softmax/weighted-sum over lfb
        if (l == 0)
            flash_chunk<1><<<4096, blk, 0, stream>>>(lfb, nullptr, lfb16, thetal, scale, up, wm, wz);
        else
            flash_chunk<0><<<4096, blk, 0, stream>>>(nullptr, lfb16, nullptr, thetal, scale, up, wm, wz);
        flash_comb<<<512, blk, 0, stream>>>(up, wm, wz, u);
        // s = u @ Wl^T + bl
        gemv_main<0><<<1024, blk, 0, stream>>>(u, Wl, PA);
        combine<1,0,0><<<128, blk, 0, stream>>>(PA, bl, theta, nullptr, 0);
        // t = s @ Wg^T + bg (bg added in LN kernel); r = relu(LN(t))
        gemv_main<0><<<1024, blk, 0, stream>>>(theta, Wg, PA);
        ln_relu_part<<<64, blk, 0, stream>>>(PA, bg, r);
        // A += r @ Wo^T + bo   (last layer also writes out + loss)
        gemv_main<0><<<1024, blk, 0, stream>>>(r, Wo, PA);
        if (l < 2)
            combine<1,1,0><<<128, blk, 0, stream>>>(PA, bo, A, nullptr, 0);
        else
            combine<1,1,1><<<128, blk, 0, stream>>>(PA, bo, A, out, has_loss);
    }
}

// Round 7
// 408.563 us; speedup vs baseline: 10.7343x; 1.3937x over previous
//
#include <hip/hip_runtime.h>

#define Bdim 64
#define Ndim 512
#define Hdim 2048
#define KSPLIT 8
#define NCHUNK 8
#define LNEPS 1e-5f
#define WMAT_ELEMS (Hdim * Hdim)

typedef unsigned short u16;
typedef __attribute__((ext_vector_type(8))) short short8;
typedef __attribute__((ext_vector_type(4))) float f32x4;

__device__ __forceinline__ u16 f2bf(float f) {
    unsigned int u = __float_as_uint(f);
    return (u16)((u + 0x7FFFu + ((u >> 16) & 1u)) >> 16);
}
__device__ __forceinline__ float bf2f(u16 s) {
    return __uint_as_float(((unsigned int)s) << 16);
}

// One-time weight prep -> 7 bf16 matrices, ALL in [o][k] layout (k contiguous):
// mid 0..4: direct convert of Wc,Wt,Wl,Wg,Wo (stored [o][k] already)
// mid 5: bWpT[o][k] = Wp[k*H+o]   (transpose)
// mid 6: bWlT[o][k] = Wl[k*H+o]   (transpose)
__global__ __launch_bounds__(256)
void convert_w(const float* __restrict__ Wc, const float* __restrict__ Wt,
               const float* __restrict__ Wl, const float* __restrict__ Wg,
               const float* __restrict__ Wo, const float* __restrict__ Wp,
               u16* __restrict__ dst)
{
    __shared__ float L[64][65];
    const int t   = threadIdx.x;
    const int mid = blockIdx.x >> 10;
    const int tb  = blockIdx.x & 1023;
    u16* out = dst + (size_t)mid * WMAT_ELEMS;
    if (mid < 5) {
        const float* src = (mid == 0) ? Wc : (mid == 1) ? Wt : (mid == 2) ? Wl
                         : (mid == 3) ? Wg : Wo;
        const size_t base = (size_t)tb * 4096 + (size_t)t * 16;
#pragma unroll
        for (int i = 0; i < 2; ++i) {
            float4 a = *(const float4*)(src + base + i * 8);
            float4 b = *(const float4*)(src + base + i * 8 + 4);
            short8 s;
            s[0] = (short)f2bf(a.x); s[1] = (short)f2bf(a.y);
            s[2] = (short)f2bf(a.z); s[3] = (short)f2bf(a.w);
            s[4] = (short)f2bf(b.x); s[5] = (short)f2bf(b.y);
            s[6] = (short)f2bf(b.z); s[7] = (short)f2bf(b.w);
            *(short8*)(out + base + i * 8) = s;
        }
    } else {
        const float* src = (mid == 5) ? Wp : Wl;
        const int k0 = (tb & 31) * 64;
        const int o0 = (tb >> 5) * 64;
        const int row = t >> 2;          // source k-row 0..63
        const int cq  = t & 3;           // 16-col quad
#pragma unroll
        for (int i = 0; i < 4; ++i) {
            float4 v = *(const float4*)(src + (size_t)(k0 + row) * Hdim + o0 + cq * 16 + i * 4);
            *(float4*)(&L[row][cq * 16 + i * 4]) = v;
        }
        __syncthreads();
        const int orow = t >> 2;         // dest o-row 0..63
#pragma unroll
        for (int half = 0; half < 2; ++half) {
            short8 s;
#pragma unroll
            for (int i = 0; i < 8; ++i)
                s[i] = (short)f2bf(L[cq * 16 + half * 8 + i][orow]);
            *(short8*)(out + (size_t)(o0 + orow) * Hdim + k0 + cq * 16 + half * 8) = s;
        }
    }
}

// MFMA GEMV: part[ks][b][o] = sum_{k in ks-range} X[b,k] * Wb[o][k]
// X f32 [64][2048] (converted to bf16 while staging); Wb bf16 [o][k].
// Guide-verified recipe: A/B frags short8 along k (consistent slot order),
// C/D mapping col=lane&15, row=(lane>>4)*4+reg (m89).
// Grid 256 = 8 k-splits x 32 n-tiles(64). Block 256 thr = 4 waves, tile 64x64.
__global__ __launch_bounds__(256)
void mfma_gemv(const float* __restrict__ X, const u16* __restrict__ Wb,
               float* __restrict__ part)
{
    __shared__ short Xs[64][72];   // row stride 144B = 9x16B -> conflict-benign
    __shared__ short Ws[64][72];
    const int t  = threadIdx.x;
    const int nt = blockIdx.x & 31;
    const int ks = blockIdx.x >> 5;
    const int o0 = nt * 64;
    const int kb = ks * 256;
    const int wv = t >> 6;
    const int ln = t & 63;
    const int xr = t & 63;            // X stage: row
    const int xc = (t >> 6) * 16;     // X stage: 16-col group
    const int wn = t >> 2;            // W stage: o-row
    const int wk = (t & 3) * 16;      // W stage: 16-k group (32B)

    f32x4 acc[4];
#pragma unroll
    for (int i = 0; i < 4; ++i)
#pragma unroll
        for (int j = 0; j < 4; ++j) acc[i][j] = 0.f;

    float4 px[4];
    uint4  pw[2];
    auto gload = [&](int k0) {
#pragma unroll
        for (int i = 0; i < 4; ++i)
            px[i] = *(const float4*)(X + (size_t)xr * Hdim + k0 + xc + i * 4);
        pw[0] = *(const uint4*)(Wb + (size_t)(o0 + wn) * Hdim + k0 + wk);
        pw[1] = *(const uint4*)(Wb + (size_t)(o0 + wn) * Hdim + k0 + wk + 8);
    };
    auto lstore = [&]() {
#pragma unroll
        for (int i = 0; i < 2; ++i) {
            short8 s;
            s[0] = (short)f2bf(px[i*2].x);   s[1] = (short)f2bf(px[i*2].y);
            s[2] = (short)f2bf(px[i*2].z);   s[3] = (short)f2bf(px[i*2].w);
            s[4] = (short)f2bf(px[i*2+1].x); s[5] = (short)f2bf(px[i*2+1].y);
            s[6] = (short)f2bf(px[i*2+1].z); s[7] = (short)f2bf(px[i*2+1].w);
            *(short8*)(&Xs[xr][xc + i * 8]) = s;
        }
        *(uint4*)(&Ws[wn][wk])     = pw[0];
        *(uint4*)(&Ws[wn][wk + 8]) = pw[1];
    };

    gload(kb);
    for (int c = 0; c < 4; ++c) {
        __syncthreads();
        lstore();
        __syncthreads();
        if (c < 3) gload(kb + (c + 1) * 64);
#pragma unroll
        for (int kstep = 0; kstep < 2; ++kstep) {
            const int kf = kstep * 32 + (ln >> 4) * 8;
            short8 af = *(const short8*)(&Xs[16 * wv + (ln & 15)][kf]);
#pragma unroll
            for (int n4 = 0; n4 < 4; ++n4) {
                short8 bf = *(const short8*)(&Ws[n4 * 16 + (ln & 15)][kf]);
                acc[n4] = __builtin_amdgcn_mfma_f32_16x16x32_bf16(af, bf, acc[n4], 0, 0, 0);
            }
        }
    }
#pragma unroll
    for (int n4 = 0; n4 < 4; ++n4) {
#pragma unroll
        for (int r = 0; r < 4; ++r) {
            const int brow = 16 * wv + (ln >> 4) * 4 + r;
            part[(size_t)(ks * 64 + brow) * Hdim + o0 + n4 * 16 + (ln & 15)] = acc[n4][r];
        }
    }
}

// Y[b,o] (=|+=) sum_s part[s][b][o] (+ bias[o]); optionally also write out.
template<int HASBIAS, int ACC, int FINAL>
__global__ __launch_bounds__(256)
void combine(const float* __restrict__ part, const float* __restrict__ bias,
             float* __restrict__ Y, float* __restrict__ out, int has_loss)
{
    const int flat4 = blockIdx.x * 256 + threadIdx.x;   // 0..32767
    const size_t e  = (size_t)flat4 * 4;
    const int o     = (int)(e & (Hdim - 1));
    float4 v;
    if (HASBIAS) v = *(const float4*)(bias + o);
    else         v = make_float4(0.f, 0.f, 0.f, 0.f);
#pragma unroll
    for (int s = 0; s < KSPLIT; ++s) {
        float4 p = *(const float4*)(part + (size_t)s * (64 * Hdim) + e);
        v.x += p.x; v.y += p.y; v.z += p.z; v.w += p.w;
    }
    if (ACC) {
        float4 a = *(const float4*)(Y + e);
        v.x += a.x; v.y += a.y; v.z += a.z; v.w += a.w;
    }
    *(float4*)(Y + e) = v;
    if (FINAL) {
        *(float4*)(out + e) = v;
        if (has_loss && flat4 == 0) out[Bdim * Hdim] = 0.f;
    }
}

// One (b, 8-row n-chunk): scores -> local softmax -> partial weighted sum.
// FIRST: read f32 lfb and also write bf16 cache; else read bf16 cache.
template<int FIRST>
__global__ __launch_bounds__(256, 4)
void flash_chunk(const float* __restrict__ lfb, const u16* __restrict__ lfb16r,
                 u16* __restrict__ lfb16w, const float* __restrict__ thetal,
                 float scale, u16* __restrict__ up,
                 float* __restrict__ wm, float* __restrict__ wz)
{
    __shared__ u16 T[NCHUNK][Hdim];   // 32 KB
    __shared__ float th[Hdim];        // 8 KB
    __shared__ float sc[NCHUNK];
    __shared__ float wts[NCHUNK];
    const int t  = threadIdx.x;
    const int b  = blockIdx.x >> 6;
    const int ch = blockIdx.x & 63;
    const size_t nbase = (size_t)b * Ndim + ch * NCHUNK;
#pragma unroll
    for (int i = 0; i < 16; ++i) {
        int flat4 = i * 256 + t;
        int row   = flat4 >> 9;
        int c4    = flat4 & 511;
        if (FIRST) {
            float4 v = *(const float4*)(lfb + (nbase + row) * Hdim + c4 * 4);
            ushort4 u4;
            u4.x = f2bf(v.x); u4.y = f2bf(v.y); u4.z = f2bf(v.z); u4.w = f2bf(v.w);
            *(ushort4*)(&T[row][c4 * 4]) = u4;
            *(ushort4*)(lfb16w + (nbase + row) * Hdim + c4 * 4) = u4;
        } else {
            ushort4 u4 = *(const ushort4*)(lfb16r + (nbase + row) * Hdim + c4 * 4);
            *(ushort4*)(&T[row][c4 * 4]) = u4;
        }
    }
#pragma unroll
    for (int i = 0; i < 2; ++i) {
        int c = (i * 256 + t) * 4;
        float4 v = *(const float4*)(thetal + (size_t)b * Hdim + c);
        *(float4*)(&th[c]) = v;
    }
    __syncthreads();
    const int wv = t >> 6, ln = t & 63;
#pragma unroll
    for (int q = 0; q < 2; ++q) {
        int n = wv * 2 + q;
        float a = 0.f;
#pragma unroll
        for (int i = 0; i < 8; ++i) {
            int c = ln * 4 + i * 256;
            ushort4 x = *(const ushort4*)(&T[n][c]);
            float4 y  = *(const float4*)(&th[c]);
            a += bf2f(x.x) * y.x + bf2f(x.y) * y.y + bf2f(x.z) * y.z + bf2f(x.w) * y.w;
        }
#pragma unroll
        for (int off = 32; off; off >>= 1) a += __shfl_xor(a, off, 64);
        if (ln == 0) sc[n] = a * scale;
    }
    __syncthreads();
    float m = sc[0];
#pragma unroll
    for (int n = 1; n < NCHUNK; ++n) m = fmaxf(m, sc[n]);
    if (t < NCHUNK) wts[t] = expf(sc[t] - m);
    __syncthreads();
    if (t == 0) {
        float z = 0.f;
#pragma unroll
        for (int n = 0; n < NCHUNK; ++n) z += wts[n];
        wm[blockIdx.x] = m;
        wz[blockIdx.x] = z;
    }
#pragma unroll
    for (int i = 0; i < 8; ++i) {
        int c = t + i * 256;
        float a = 0.f;
#pragma unroll
        for (int n = 0; n < NCHUNK; ++n) a += wts[n] * bf2f(T[n][c]);
        up[(size_t)blockIdx.x * Hdim + c] = f2bf(a);
    }
}

__global__ __launch_bounds__(256)
void flash_comb(const u16* __restrict__ up, const float* __restrict__ wm,
                const float* __restrict__ wz, float* __restrict__ u)
{
    __shared__ float mm[64], zz[64], ee[64];
    const int t  = threadIdx.x;
    const int b  = blockIdx.x >> 3;
    const int sl = blockIdx.x & 7;
    if (t < 64) { mm[t] = wm[b * 64 + t]; zz[t] = wz[b * 64 + t]; }
    __syncthreads();
    float mg = mm[0];
#pragma unroll
    for (int i = 1; i < 64; ++i) mg = fmaxf(mg, mm[i]);
    if (t < 64) ee[t] = expf(mm[t] - mg);
    __syncthreads();
    float Z = 0.f;
#pragma unroll
    for (int i = 0; i < 64; ++i) Z += zz[i] * ee[i];
    const float inv = 1.f / Z;
    const int col = sl * 256 + t;
    float a = 0.f;
#pragma unroll 8
    for (int ch = 0; ch < 64; ++ch)
        a += ee[ch] * bf2f(up[(size_t)(b * 64 + ch) * Hdim + col]);
    u[(size_t)b * Hdim + col] = a * inv;
}

// r = relu(layernorm(sum_s part[s][b][:] + bias))
__global__ __launch_bounds__(256)
void ln_relu_part(const float* __restrict__ part, const float* __restrict__ bias,
                  float* __restrict__ r)
{
    __shared__ float trow[Hdim];
    __shared__ float red[8];
    const int t = threadIdx.x, b = blockIdx.x;
    float sum = 0.f, sq = 0.f;
#pragma unroll
    for (int i = 0; i < 2; ++i) {
        int c = (i * 256 + t) * 4;
        float4 v = *(const float4*)(bias + c);
#pragma unroll
        for (int s = 0; s < KSPLIT; ++s) {
            float4 p = *(const float4*)(part + ((size_t)(s * 64 + b)) * Hdim + c);
            v.x += p.x; v.y += p.y; v.z += p.z; v.w += p.w;
        }
        *(float4*)(&trow[c]) = v;
        sum += v.x + v.y + v.z + v.w;
        sq  += v.x * v.x + v.y * v.y + v.z * v.z + v.w * v.w;
    }
#pragma unroll
    for (int off = 32; off; off >>= 1) {
        sum += __shfl_xor(sum, off, 64);
        sq  += __shfl_xor(sq,  off, 64);
    }
    if ((t & 63) == 0) { red[t >> 6] = sum; red[4 + (t >> 6)] = sq; }
    __syncthreads();
    sum = red[0] + red[1] + red[2] + red[3];
    sq  = red[4] + red[5] + red[6] + red[7];
    const float mu   = sum * (1.f / Hdim);
    const float var  = sq * (1.f / Hdim) - mu * mu;
    const float rstd = rsqrtf(var + LNEPS);
#pragma unroll
    for (int i = 0; i < 2; ++i) {
        int c = (i * 256 + t) * 4;
        float4 v = *(const float4*)(&trow[c]);
        float4 o;
        o.x = fmaxf(0.f, (v.x - mu) * rstd);
        o.y = fmaxf(0.f, (v.y - mu) * rstd);
        o.z = fmaxf(0.f, (v.z - mu) * rstd);
        o.w = fmaxf(0.f, (v.w - mu) * rstd);
        *(float4*)(r + (size_t)b * Hdim + c) = o;
    }
}

extern "C" void kernel_launch(void* const* d_in, const int* in_sizes, int n_in,
                              void* d_out, int out_size, void* d_ws, size_t ws_size,
                              hipStream_t stream) {
    (void)in_sizes; (void)n_in; (void)ws_size;
    const float* clip = (const float*)d_in[0];
    const float* lfb  = (const float*)d_in[1];
    const float* Wc   = (const float*)d_in[2];
    const float* bc   = (const float*)d_in[3];
    const float* Wl   = (const float*)d_in[4];
    const float* bl   = (const float*)d_in[5];
    const float* Wt   = (const float*)d_in[6];
    const float* bt   = (const float*)d_in[7];
    const float* Wp   = (const float*)d_in[8];
    // d_in[9] = bp: cancels in softmax (per-row constant) -> unused
    const float* Wg   = (const float*)d_in[10];
    const float* bg   = (const float*)d_in[11];
    const float* Wo   = (const float*)d_in[12];
    const float* bo   = (const float*)d_in[13];
    float* out = (float*)d_out;

    // Workspace layout in f32 slots; u16 buffers counted in f32 slots.
    float* wsf    = (float*)d_ws;
    float* A      = wsf;
    float* theta  = wsf + 131072;
    float* thetap = wsf + 262144;
    float* thetal = wsf + 393216;
    float* u      = wsf + 524288;
    float* r      = wsf + 655360;
    float* PA     = wsf + 786432;            // 8*64*2048 = 1048576 -> end 1835008
    float* wm     = wsf + 1835008;           // 4096
    float* wz     = wsf + 1839104;           // 4096
    u16*   up     = (u16*)(wsf + 1843200);   // 4096*2048 u16 = 4194304 f32 -> end 6037504
    u16*   lfb16  = (u16*)(wsf + 6037504);   // 64*512*2048 u16 = 33554432 f32 -> end 39591936
    u16*   Wbf    = (u16*)(wsf + 39591936);  // 7 * 2048^2 u16 (~217 MB total ws)

    u16* bWc  = Wbf + (size_t)0 * WMAT_ELEMS;
    u16* bWt  = Wbf + (size_t)1 * WMAT_ELEMS;
    u16* bWl  = Wbf + (size_t)2 * WMAT_ELEMS;
    u16* bWg  = Wbf + (size_t)3 * WMAT_ELEMS;
    u16* bWo  = Wbf + (size_t)4 * WMAT_ELEMS;
    u16* bWpT = Wbf + (size_t)5 * WMAT_ELEMS;
    u16* bWlT = Wbf + (size_t)6 * WMAT_ELEMS;

    const float scale = 0.022097086912079608f;   // 1/sqrt(2048)
    dim3 blk(256);
    const int has_loss = (out_size > Bdim * Hdim) ? 1 : 0;

    // one-time: bf16 weight views
    convert_w<<<7168, blk, 0, stream>>>(Wc, Wt, Wl, Wg, Wo, Wp, Wbf);

    // A = clip @ Wc^T + bc
    mfma_gemv<<<256, blk, 0, stream>>>(clip, bWc, PA);
    combine<1,0,0><<<128, blk, 0, stream>>>(PA, bc, A, nullptr, 0);

    for (int l = 0; l < 3; ++l) {
        // theta = A @ Wt^T + bt
        mfma_gemv<<<256, blk, 0, stream>>>(A, bWt, PA);
        combine<1,0,0><<<128, blk, 0, stream>>>(PA, bt, theta, nullptr, 0);
        // thetap = theta @ Wp
        mfma_gemv<<<256, blk, 0, stream>>>(theta, bWpT, PA);
        combine<0,0,0><<<128, blk, 0, stream>>>(PA, nullptr, thetap, nullptr, 0);
        // thetal = thetap @ Wl
        mfma_gemv<<<256, blk, 0, stream>>>(thetap, bWlT, PA);
        combine<0,0,0><<<128, blk, 0, stream>>>(PA, nullptr, thetal, nullptr, 0);
        // fused scores/softmax/weighted-sum over lfb
        if (l == 0)
            flash_chunk<1><<<4096, blk, 0, stream>>>(lfb, nullptr, lfb16, thetal, scale, up, wm, wz);
        else
            flash_chunk<0><<<4096, blk, 0, stream>>>(nullptr, lfb16, nullptr, thetal, scale, up, wm, wz);
        flash_comb<<<512, blk, 0, stream>>>(up, wm, wz, u);
        // s = u @ Wl^T + bl
        mfma_gemv<<<256, blk, 0, stream>>>(u, bWl, PA);
        combine<1,0,0><<<128, blk, 0, stream>>>(PA, bl, theta, nullptr, 0);
        // t = s @ Wg^T + bg (bg added in LN kernel); r = relu(LN(t))
        mfma_gemv<<<256, blk, 0, stream>>>(theta, bWg, PA);
        ln_relu_part<<<64, blk, 0, stream>>>(PA, bg, r);
        // A += r @ Wo^T + bo   (last layer also writes out + loss)
        mfma_gemv<<<256, blk, 0, stream>>>(r, bWo, PA);
        if (l < 2)
            combine<1,1,0><<<128, blk, 0, stream>>>(PA, bo, A, nullptr, 0);
        else
            combine<1,1,1><<<128, blk, 0, stream>>>(PA, bo, A, out, has_loss);
    }
}